// Round 13
// baseline (10441.931 us; speedup 1.0000x reference)
//
#include <hip/hip_runtime.h>
#include <hip/hip_bf16.h>

// Problem constants
#define SEQ  256
#define BSZ  128
#define DM   512
#define HID  1536
#define KTOT 2560      // x(512) | r(512) | h(1536)
#define VC   6144      // virtual cols: [0,3072) fused rz, [3072,4608) inn, [4608,6144) hn
#define NBLK 720       // persistent grid = 45 groups x 16

typedef __attribute__((ext_vector_type(4))) float f32x4;
typedef __attribute__((ext_vector_type(8))) short short8;
typedef __attribute__((ext_vector_type(4))) unsigned short us4;
typedef __attribute__((ext_vector_type(8))) unsigned short us8;
typedef __attribute__((ext_vector_type(4))) unsigned int u32x4;

// ws layout (bytes)
#define OFF_WBH 0ull                 // bf16 [4608][2560]      = 23,592,960
#define OFF_P   47185920ull          // f32  [5][128][6144]    = 15,728,640
#define OFF_R32 62914560ull          // f32  [128][512]  (written only at t=255)
#define OFF_RBH 80740352ull          // bf16 [128][512]        (zeroed)
#define OFF_HBH 81002496ull          // bf16 [128][1536]       (zeroed)
#define OFF_BAR 81788928ull          // 1024 uints: root@0, ep@32, gcnt[g]@64+g*16, xcdcnt@832+x*16
// pk_zero region: OFF_RBH..OFF_BAR = 1,048,576 B = 65,536 x 16B = 256 blocks x 256

static __device__ __forceinline__ unsigned short bf(float x) {
  __hip_bfloat16 h = __float2bfloat16(x);
  return *reinterpret_cast<unsigned short*>(&h);
}

// ---- cross-XCD coherence helpers. Policy: the per-XCD L2 is reserved for W.
// Everything else is marked nt (evict-first) and/or LLC-direct (sc0|sc1).
static __device__ __forceinline__ void stf_llc(float* p, float v) {   // P partials
  asm volatile("global_store_dword %0, %1, off sc0 sc1 nt" :: "v"(p), "v"(v) : "memory");
}
static __device__ __forceinline__ void st16_llc(unsigned short* p, unsigned short v) {
  unsigned vv = v;
  asm volatile("global_store_short %0, %1, off sc0 sc1" :: "v"(p), "v"(vv) : "memory");
}
static __device__ __forceinline__ float ldf_llc(const float* p) {
  return __hip_atomic_load(p, __ATOMIC_RELAXED, __HIP_MEMORY_SCOPE_SYSTEM);
}
static __device__ __forceinline__ void ld1x16_llc_nt(const unsigned short* p, u32x4& r0) {
  asm volatile(
      "global_load_dwordx4 %0, %1, off sc0 sc1 nt\n\t"
      "s_waitcnt vmcnt(0)"
      : "=&v"(r0) : "v"(p) : "memory");
}
static __device__ __forceinline__ f32x4 ntl4(const float* p) {        // x input
  return __builtin_nontemporal_load((const f32x4*)p);
}
static __device__ __forceinline__ unsigned sysld(unsigned* p) {
  return __hip_atomic_load(p, __ATOMIC_RELAXED, __HIP_MEMORY_SCOPE_SYSTEM);
}

// ---- grid barrier: hierarchical RMW arrive at LLC + SYSTEM poll. NO cache fences.
static __device__ __forceinline__ void gsync(unsigned* bar) {
  asm volatile("s_waitcnt vmcnt(0)" ::: "memory");   // drain inline-asm stores
  __syncthreads();
  if (threadIdx.x == 0) {
    unsigned* root = bar;
    unsigned* ep   = bar + 32;
    unsigned* gcnt = bar + 64 + (blockIdx.x >> 4) * 16;   // 45 groups x 16
    unsigned e = sysld(ep);
    if (atomicAdd(gcnt, 1u) == 15u) {
      atomicSub(gcnt, 16u);
      if (atomicAdd(root, 1u) == 44u) {
        atomicSub(root, 45u);
        atomicAdd(ep, 1u);
      }
    }
    while (sysld(ep) == e) __builtin_amdgcn_s_sleep(8);
  }
  __syncthreads();
}

// ---------------- prep: repack weights to bf16 [4608][2560]; zero barrier ----------------
__global__ __launch_bounds__(256) void pk_wb(const float* __restrict__ Wih,
                                             const float* __restrict__ Whh,
                                             unsigned short* __restrict__ Wh,
                                             unsigned* __restrict__ bar) {
  if (blockIdx.x == 0)
    for (int i = threadIdx.x; i < 1024; i += 256) bar[i] = 0u;
  int idx = blockIdx.x * 256 + threadIdx.x;        // < 4608*640 = 2,949,120
  int row = idx / 640;
  int k = (idx - row * 640) * 4;
  const float* src = (k < 1024) ? (Wih + (size_t)row * 1024 + k)
                                : (Whh + (size_t)row * HID + (k - 1024));
  f32x4 v = *(const f32x4*)src;
  us4 oh;
#pragma unroll
  for (int i = 0; i < 4; ++i) oh[i] = bf(v[i]);
  *(us4*)(Wh + (size_t)row * KTOT + k) = oh;
}

__global__ __launch_bounds__(256) void pk_zero(f32x4* __restrict__ dst) {
  f32x4 z = {0.f, 0.f, 0.f, 0.f};
  dst[(size_t)blockIdx.x * 256 + threadIdx.x] = z;
}

// ---------------- persistent fused kernel: 256 x (GEMM | pair) ----------------
// 720 blocks x 256 threads, 3/CU. Tile [64b x 64j x 512k]; 720 tasks = 8 XCD x 90.
// XCD g owns rz jg[6g,6g+6) + inn jg[48+3g,..+3) + hn jg[72+3g,..+3): its ~2.9 MB
// W slice is the ONLY plain-cached data -> stays warm in the XCD's 4 MB L2.
// x/acts/P are nt and/or LLC-direct so they never evict W.
__global__ __launch_bounds__(256, 3) void fused(
    const float* __restrict__ x, const float* __restrict__ bih,
    const float* __restrict__ bhh, char* __restrict__ ws,
    float* __restrict__ dout)
{
  const unsigned short* Wh = (const unsigned short*)(ws + OFF_WBH);
  float*          P   = (float*)(ws + OFF_P);
  float*          r32 = (float*)(ws + OFF_R32);
  unsigned short* Rbh = (unsigned short*)(ws + OFF_RBH);
  unsigned short* Hbh = (unsigned short*)(ws + OFF_HBH);
  unsigned* bar = (unsigned*)(ws + OFF_BAR);

  const int blk = blockIdx.x;
  const int tid = threadIdx.x;

  // ---- XCD rendezvous: fixed rank within this physical XCD ----
  unsigned xcd;
  asm volatile("s_getreg_b32 %0, hwreg(HW_REG_XCC_ID)" : "=s"(xcd));
  xcd &= 7;
  __shared__ unsigned rankS;
  if (tid == 0) rankS = atomicAdd(&bar[832 + xcd * 16], 1u);
  __syncthreads();
  const unsigned rank = rankS;

  const int wave = tid >> 6, lane = tid & 63;
  const int jh  = wave * 16;              // wave's 16-col slice of the 64-col tile
  const int l15 = lane & 15, kg = lane >> 4;
  const int sr_ = tid >> 2;               // staging row 0..63
  const int sc_ = (tid & 3) * 8;          // staging col (8 shorts per thread)

  __shared__ __align__(16) unsigned short AH[64 * 40];
  __shared__ __align__(16) float Alds[2][64 * 65];   // per-pair fast weights
  __shared__ float kS[2][64];
  __shared__ float qS[2][64];

  // ---- init: zero A (LDS) ----
  for (int i = tid; i < 2 * 64 * 65; i += 256) ((float*)Alds)[i] = 0.f;
  float hprev[3] = {0.f, 0.f, 0.f};       // per-pair-lane GRU state (waves 0,1 of blk<512)
  gsync(bar);                             // also: all ranks registered
  const unsigned cnt_g = sysld(&bar[832 + xcd * 16]);

  for (int t = 0; t < SEQ; ++t) {
    // ===== GEMM phase: this XCD's 90 tasks, strided over its blocks =====
    for (unsigned v = rank; v < 90u; v += cnt_g) {
      int jg, ks, half;
      if (v < 60u)      { jg = 6 * xcd + v / 10;                unsigned r = v % 10; ks = r >> 1; half = r & 1; }
      else if (v < 72u) { unsigned w = v - 60; jg = 48 + 3 * xcd + w / 4; unsigned r = w % 4; ks = r >> 1;       half = r & 1; }
      else              { unsigned w = v - 72; jg = 72 + 3 * xcd + w / 6; unsigned r = w % 6; ks = 2 + (r >> 1); half = r & 1; }
      int colb, wrowb;
      if (jg < 48)      { colb = jg * 64;               wrowb = colb; }          // rz
      else if (jg < 72) { colb = 3072 + (jg - 48) * 64; wrowb = colb; }          // inn
      else              { colb = 4608 + (jg - 72) * 64; wrowb = colb - 1536; }   // hn
      const int kc0 = ks * 512;
      const int b0g = half * 64;
      const int wrow0 = wrowb + jh;

      f32x4 acc[4];
#pragma unroll
      for (int i = 0; i < 4; ++i) acc[i] = (f32x4){0.f, 0.f, 0.f, 0.f};

      for (int it = 0; it < 16; ++it) {
        int kabs = kc0 + it * 32;
        us8 h0;                       // x path
        u32x4 a0;                     // r/h path (same bytes)
        if (ks == 0) {                // K [0,512): x (f32 -> bf16), nt: don't pollute L2
          const float* p = x + ((size_t)(t * BSZ + b0g + sr_)) * DM + kabs + sc_;
          f32x4 f0 = ntl4(p);
          f32x4 f1 = ntl4(p + 4);
#pragma unroll
          for (int i = 0; i < 4; ++i) {
            h0[i]     = bf(f0[i]);
            h0[4 + i] = bf(f1[i]);
          }
        } else if (ks == 1) {         // K [512,1024): r (bf16, LLC-fresh, nt)
          size_t off = (size_t)(b0g + sr_) * DM + (kabs - 512) + sc_;
          ld1x16_llc_nt(Rbh + off, a0);
        } else {                      // K [1024,2560): h (bf16, LLC-fresh, nt)
          size_t off = (size_t)(b0g + sr_) * HID + (kabs - 1024) + sc_;
          ld1x16_llc_nt(Hbh + off, a0);
        }
        __syncthreads();
        if (ks == 0) *(us8*)&AH[sr_ * 40 + sc_]   = h0;
        else         *(u32x4*)&AH[sr_ * 40 + sc_] = a0;
        __syncthreads();

        size_t woff = (size_t)(wrow0 + l15) * KTOT + kabs + kg * 8;
        short8 wh_ = *(const short8*)(Wh + woff);   // plain: L2-resident W slice
#pragma unroll
        for (int bt = 0; bt < 4; ++bt) {
          short8 ah = *(const short8*)&AH[(bt * 16 + l15) * 40 + kg * 8];
          acc[bt] = __builtin_amdgcn_mfma_f32_16x16x32_bf16(ah, wh_, acc[bt], 0, 0, 0);
        }
      }
      // P partials: write THROUGH to LLC, nt (cross-XCD consumers read within ~10us)
#pragma unroll
      for (int bt = 0; bt < 4; ++bt)
#pragma unroll
        for (int i = 0; i < 4; ++i)
          stf_llc(&P[((size_t)ks * BSZ + b0g + bt * 16 + kg * 4 + i) * VC + colb + jh + l15],
                  acc[bt][i]);
    }
    gsync(bar);

    // ================= pair phase (blocks 0..511, waves 0..1, 1 pair each) ==========
    if (blk < 512 && wave < 2) {
      const int pair = blk * 2 + wave;
      const int b = pair >> 3, n = pair & 7;
      const int l = lane;
      const float* Pb = P + (size_t)b * VC;
      float hv[3];
#pragma unroll
      for (int s = 0; s < 3; ++s) {
        int c = s * 512 + n * 64 + l;
        float sr2 = 0.f, sz = 0.f;
#pragma unroll
        for (int ksi = 0; ksi < 5; ++ksi) {
          const float* q = Pb + (size_t)ksi * BSZ * VC;
          sr2 += ldf_llc(q + c);
          sz  += ldf_llc(q + 1536 + c);
        }
        float gin = ldf_llc(Pb + 3072 + c) + ldf_llc(Pb + (size_t)BSZ * VC + 3072 + c);
        float ghn = 0.f;
#pragma unroll
        for (int ksi = 2; ksi < 5; ++ksi)
          ghn += ldf_llc(Pb + (size_t)ksi * BSZ * VC + 4608 + c);
        float rg = 1.f / (1.f + __expf(-(sr2 + bih[c] + bhh[c])));
        float zg = 1.f / (1.f + __expf(-(sz + bih[1536 + c] + bhh[1536 + c])));
        float nn = tanhf(gin + bih[3072 + c] + rg * (ghn + bhh[3072 + c]));
        float hnew = (1.f - zg) * nn + zg * hprev[s];
        hprev[s] = hnew;
        size_t hix = (size_t)b * HID + c;
        st16_llc(&Hbh[hix], bf(hnew));
        hv[s] = hnew;
      }
      float ssq = hv[0] * hv[0], ssk = hv[1] * hv[1];
#pragma unroll
      for (int off = 32; off > 0; off >>= 1) {
        ssq += __shfl_xor(ssq, off);
        ssk += __shfl_xor(ssk, off);
      }
      float qn = hv[0] * rsqrtf(ssq);
      float kn = hv[1] * rsqrtf(ssk);
      float ke = kn > 0.f ? kn : expm1f(kn);   // elu(unitnorm)
      kS[wave][l] = ke;
      qS[wave][l] = qn;                        // wave-local LDS: lockstep, no block sync

      float vvl = hv[2];
      float* Arow = &Alds[wave][l * 65];       // stride 65: 2 lanes/bank = conflict-free
      float racc = 0.f;
#pragma unroll
      for (int q4 = 0; q4 < 16; ++q4) {
        float a0 = Arow[q4 * 4 + 0], a1 = Arow[q4 * 4 + 1];
        float a2 = Arow[q4 * 4 + 2], a3 = Arow[q4 * 4 + 3];
        float k0 = kS[wave][q4 * 4 + 0], k1 = kS[wave][q4 * 4 + 1];
        float k2 = kS[wave][q4 * 4 + 2], k3 = kS[wave][q4 * 4 + 3];
        float q0 = qS[wave][q4 * 4 + 0], q1 = qS[wave][q4 * 4 + 1];
        float q2 = qS[wave][q4 * 4 + 2], q3 = qS[wave][q4 * 4 + 3];
        a0 += k0 * vvl; a1 += k1 * vvl; a2 += k2 * vvl; a3 += k3 * vvl;
        racc += q0 * a0 + q1 * a1 + q2 * a2 + q3 * a3;
        Arow[q4 * 4 + 0] = a0; Arow[q4 * 4 + 1] = a1;
        Arow[q4 * 4 + 2] = a2; Arow[q4 * 4 + 3] = a3;
      }
      size_t ri = (size_t)b * DM + n * 64 + l;
      st16_llc(&Rbh[ri], bf(racc));

      if (t == SEQ - 1) {
        r32[ri] = racc;                        // final r (plain; kernel-end flush)
        dout[65536  + pair * 64 + l] = ke;     // k output (f32)
        dout[131072 + pair * 64 + l] = qn;     // q output (f32)
      }
    }
    gsync(bar);
  }
}

// ---------------- final: out = r @ Wo.T + bo (f32) ----------------
__global__ __launch_bounds__(512) void out_gemm(const float* __restrict__ r32,
                                                const float* __restrict__ Wo,
                                                const float* __restrict__ bo,
                                                float* __restrict__ dout) {
  int b0 = blockIdx.x * 2;
  int o  = threadIdx.x;
  __shared__ float rL0[512];
  __shared__ float rL1[512];
  rL0[o] = r32[(size_t)b0 * DM + o];
  rL1[o] = r32[(size_t)(b0 + 1) * DM + o];
  __syncthreads();
  float a0 = bo[o], a1 = a0;
  const float* wrow = Wo + (size_t)o * DM;
  for (int c = 0; c < DM; ++c) {
    float w = wrow[c];
    a0 += rL0[c] * w;
    a1 += rL1[c] * w;
  }
  dout[(size_t)b0 * DM + o]       = a0;
  dout[(size_t)(b0 + 1) * DM + o] = a1;
}

extern "C" void kernel_launch(void* const* d_in, const int* in_sizes, int n_in,
                              void* d_out, int out_size, void* d_ws, size_t ws_size,
                              hipStream_t stream) {
  // Defensive input identification by element count (deterministic).
  int ix = 0, iwih = 1, iwhh = 2, ibih = 3, ibhh = 4, iwo = 5, ibo = 6;
  {
    int b1 = -1, b2 = -1;
    for (int i = 0; i < n_in; ++i) {
      int s = in_sizes[i];
      if      (s == SEQ * BSZ * DM) ix = i;
      else if (s == 4608 * 1024)    iwih = i;
      else if (s == 4608 * 1536)    iwhh = i;
      else if (s == DM * DM)        iwo = i;
      else if (s == DM)             ibo = i;
      else if (s == 4608)           { if (b1 < 0) b1 = i; else b2 = i; }
    }
    if (b1 >= 0) ibih = b1;
    if (b2 >= 0) ibhh = b2;
  }
  const float* x   = (const float*)d_in[ix];
  const float* Wih = (const float*)d_in[iwih];
  const float* Whh = (const float*)d_in[iwhh];
  const float* bih = (const float*)d_in[ibih];
  const float* bhh = (const float*)d_in[ibhh];
  const float* Wo  = (const float*)d_in[iwo];
  const float* bo  = (const float*)d_in[ibo];

  char* ws = (char*)d_ws;
  unsigned short* Wh  = (unsigned short*)(ws + OFF_WBH);
  float*          r32 = (float*)(ws + OFF_R32);
  unsigned*       bar = (unsigned*)(ws + OFF_BAR);
  float* dout = (float*)d_out;

  pk_wb  <<<11520, 256, 0, stream>>>(Wih, Whh, Wh, bar);
  pk_zero<<<256,   256, 0, stream>>>((f32x4*)(ws + OFF_RBH));
  fused  <<<NBLK,  256, 0, stream>>>(x, bih, bhh, ws, dout);
  out_gemm<<<64, 512, 0, stream>>>(r32, Wo, bo, dout);
}

// Round 14
// 7102.374 us; speedup vs baseline: 1.4702x; 1.4702x over previous
//
#include <hip/hip_runtime.h>
#include <hip/hip_bf16.h>

// Problem constants
#define SEQ  256
#define BSZ  128
#define DM   512
#define HID  1536
#define KTOT 2560      // x(512) | r(512) | h(1536)
#define VC   6144      // virtual cols: [0,3072) fused rz, [3072,4608) inn, [4608,6144) hn
#define NBLK 720       // persistent grid = 45 groups x 16

typedef __attribute__((ext_vector_type(4))) float f32x4;
typedef __attribute__((ext_vector_type(8))) short short8;
typedef __attribute__((ext_vector_type(4))) unsigned short us4;
typedef __attribute__((ext_vector_type(8))) unsigned short us8;
typedef __attribute__((ext_vector_type(4))) unsigned int u32x4;

// ws layout (bytes)
#define OFF_WBH 0ull                 // bf16 [4608][2560]      = 23,592,960
#define OFF_P   47185920ull          // f32  [5][128][6144]    = 15,728,640
#define OFF_R32 62914560ull          // f32  [128][512]  (written only at t=255)
#define OFF_RBH 80740352ull          // bf16 [128][512]        (zeroed)
#define OFF_HBH 81002496ull          // bf16 [128][1536]       (zeroed)
#define OFF_BAR 81788928ull          // 1024 uints: root@0, ep@32, gcnt[g]@64+g*16, xcdcnt@832+x*16
// pk_zero region: OFF_RBH..OFF_BAR = 1,048,576 B = 65,536 x 16B = 256 blocks x 256

static __device__ __forceinline__ unsigned short bf(float x) {
  __hip_bfloat16 h = __float2bfloat16(x);
  return *reinterpret_cast<unsigned short*>(&h);
}

// ---- coherence policy: per-XCD L2 is reserved for W (plain loads).
// x/acts: sc0|sc1 loads (LLC-direct, no L2 allocate). P/Hb/Rb: sc0|sc1 write-through.
static __device__ __forceinline__ void stf_llc(float* p, float v) {   // P partials
  asm volatile("global_store_dword %0, %1, off sc0 sc1" :: "v"(p), "v"(v) : "memory");
}
static __device__ __forceinline__ void st16_llc(unsigned short* p, unsigned short v) {
  unsigned vv = v;
  asm volatile("global_store_short %0, %1, off sc0 sc1" :: "v"(p), "v"(vv) : "memory");
}
static __device__ __forceinline__ float ldf_llc(const float* p) {
  return __hip_atomic_load(p, __ATOMIC_RELAXED, __HIP_MEMORY_SCOPE_SYSTEM);
}
static __device__ __forceinline__ unsigned sysld(unsigned* p) {
  return __hip_atomic_load(p, __ATOMIC_RELAXED, __HIP_MEMORY_SCOPE_SYSTEM);
}

// ---- async issue helpers (NO embedded waits — counted vmcnt in the k-loop) ----
// bf16 acts path: acts (LLC-direct) + W (plain, L2-cached)
#define ISSUE_B(j, a_, w_)                                              \
  asm volatile("global_load_dwordx4 %0, %2, off sc0 sc1\n\t"           \
               "global_load_dwordx4 %1, %3, off"                        \
               : "=&v"(a_), "=&v"(w_)                                   \
               : "v"(actbase + (j) * 32), "v"(wbase + (j) * 32)         \
               : "memory");
// x path: 2x f32 dwordx4 (LLC-direct) + W (plain)
#define ISSUE_X(j, f0_, f1_, w_)                                        \
  asm volatile("global_load_dwordx4 %0, %3, off sc0 sc1\n\t"           \
               "global_load_dwordx4 %1, %4, off sc0 sc1\n\t"           \
               "global_load_dwordx4 %2, %5, off"                        \
               : "=&v"(f0_), "=&v"(f1_), "=&v"(w_)                      \
               : "v"(xbase + (j) * 32), "v"(xbase + (j) * 32 + 4),      \
                 "v"(wbase + (j) * 32)                                  \
               : "memory");

// ---- grid barrier: hierarchical RMW arrive at LLC + SYSTEM poll. NO cache fences.
static __device__ __forceinline__ void gsync(unsigned* bar) {
  asm volatile("s_waitcnt vmcnt(0)" ::: "memory");   // drain inline-asm stores
  __syncthreads();
  if (threadIdx.x == 0) {
    unsigned* root = bar;
    unsigned* ep   = bar + 32;
    unsigned* gcnt = bar + 64 + (blockIdx.x >> 4) * 16;   // 45 groups x 16
    unsigned e = sysld(ep);
    if (atomicAdd(gcnt, 1u) == 15u) {
      atomicSub(gcnt, 16u);
      if (atomicAdd(root, 1u) == 44u) {
        atomicSub(root, 45u);
        atomicAdd(ep, 1u);
      }
    }
    while (sysld(ep) == e) __builtin_amdgcn_s_sleep(8);
  }
  __syncthreads();
}

// ---------------- prep: repack weights to bf16 [4608][2560]; zero barrier ----------------
__global__ __launch_bounds__(256) void pk_wb(const float* __restrict__ Wih,
                                             const float* __restrict__ Whh,
                                             unsigned short* __restrict__ Wh,
                                             unsigned* __restrict__ bar) {
  if (blockIdx.x == 0)
    for (int i = threadIdx.x; i < 1024; i += 256) bar[i] = 0u;
  int idx = blockIdx.x * 256 + threadIdx.x;        // < 4608*640 = 2,949,120
  int row = idx / 640;
  int k = (idx - row * 640) * 4;
  const float* src = (k < 1024) ? (Wih + (size_t)row * 1024 + k)
                                : (Whh + (size_t)row * HID + (k - 1024));
  f32x4 v = *(const f32x4*)src;
  us4 oh;
#pragma unroll
  for (int i = 0; i < 4; ++i) oh[i] = bf(v[i]);
  *(us4*)(Wh + (size_t)row * KTOT + k) = oh;
}

__global__ __launch_bounds__(256) void pk_zero(f32x4* __restrict__ dst) {
  f32x4 z = {0.f, 0.f, 0.f, 0.f};
  dst[(size_t)blockIdx.x * 256 + threadIdx.x] = z;
}

// ---------------- persistent fused kernel: 256 x (GEMM | pair) ----------------
// 720 blocks x 256 threads, 3/CU. Tile [64b x 64j x 512k]; 720 tasks = 8 XCD x 90.
// XCD-pinned W slices (~2.9 MB) are the ONLY L2-allocating loads. GEMM k-loop is
// depth-2 software-pipelined: counted vmcnt + raw s_barrier (no vmcnt drain).
__global__ __launch_bounds__(256, 3) void fused(
    const float* __restrict__ x, const float* __restrict__ bih,
    const float* __restrict__ bhh, char* __restrict__ ws,
    float* __restrict__ dout)
{
  const unsigned short* Wh = (const unsigned short*)(ws + OFF_WBH);
  float*          P   = (float*)(ws + OFF_P);
  float*          r32 = (float*)(ws + OFF_R32);
  unsigned short* Rbh = (unsigned short*)(ws + OFF_RBH);
  unsigned short* Hbh = (unsigned short*)(ws + OFF_HBH);
  unsigned* bar = (unsigned*)(ws + OFF_BAR);

  const int blk = blockIdx.x;
  const int tid = threadIdx.x;

  // ---- XCD rendezvous: fixed rank within this physical XCD ----
  unsigned xcd;
  asm volatile("s_getreg_b32 %0, hwreg(HW_REG_XCC_ID)" : "=s"(xcd));
  xcd &= 7;
  __shared__ unsigned rankS;
  if (tid == 0) rankS = atomicAdd(&bar[832 + xcd * 16], 1u);
  __syncthreads();
  const unsigned rank = rankS;

  const int wave = tid >> 6, lane = tid & 63;
  const int jh  = wave * 16;              // wave's 16-col slice of the 64-col tile
  const int l15 = lane & 15, kg = lane >> 4;
  const int sr_ = tid >> 2;               // staging row 0..63
  const int sc_ = (tid & 3) * 8;          // staging col (8 shorts per thread)

  __shared__ __align__(16) unsigned short AH[2][64 * 40];   // double-buffered staging
  __shared__ __align__(16) float Alds[2][64 * 65];          // per-pair fast weights
  __shared__ float kS[2][64];
  __shared__ float qS[2][64];

  // ---- init: zero A (LDS) ----
  for (int i = tid; i < 2 * 64 * 65; i += 256) ((float*)Alds)[i] = 0.f;
  float hprev[3] = {0.f, 0.f, 0.f};       // per-pair-lane GRU state (waves 0,1 of blk<512)
  gsync(bar);                             // also: all ranks registered
  const unsigned cnt_g = sysld(&bar[832 + xcd * 16]);

  for (int t = 0; t < SEQ; ++t) {
    // ===== GEMM phase: this XCD's 90 tasks, strided over its blocks =====
    for (unsigned v = rank; v < 90u; v += cnt_g) {
      int jg, ks, half;
      if (v < 60u)      { jg = 6 * xcd + v / 10;                unsigned r = v % 10; ks = r >> 1; half = r & 1; }
      else if (v < 72u) { unsigned w = v - 60; jg = 48 + 3 * xcd + w / 4; unsigned r = w % 4; ks = r >> 1;       half = r & 1; }
      else              { unsigned w = v - 72; jg = 72 + 3 * xcd + w / 6; unsigned r = w % 6; ks = 2 + (r >> 1); half = r & 1; }
      int colb, wrowb;
      if (jg < 48)      { colb = jg * 64;               wrowb = colb; }          // rz
      else if (jg < 72) { colb = 3072 + (jg - 48) * 64; wrowb = colb; }          // inn
      else              { colb = 4608 + (jg - 72) * 64; wrowb = colb - 1536; }   // hn
      const int kc0 = ks * 512;
      const int b0g = half * 64;
      const int wrow0 = wrowb + jh;

      const unsigned short* wbase = Wh + (size_t)(wrow0 + l15) * KTOT + kc0 + kg * 8;

      f32x4 acc[4];
#pragma unroll
      for (int i = 0; i < 4; ++i) acc[i] = (f32x4){0.f, 0.f, 0.f, 0.f};

      asm volatile("s_waitcnt vmcnt(0)" ::: "memory");   // clean slate (prev task's P stores)

      if (ks == 0) {
        // ---- x path: f32 -> bf16, depth-2 pipeline, 3 loads/iter ----
        const float* xbase = x + ((size_t)(t * BSZ + b0g + sr_)) * DM + kc0 + sc_;
        u32x4 fA0, fA1, wA, fB0, fB1, wB;
        ISSUE_X(0, fA0, fA1, wA);
        ISSUE_X(1, fB0, fB1, wB);
#pragma unroll
        for (int it = 0; it < 16; ++it) {
          if (it < 15) asm volatile("s_waitcnt vmcnt(3)" ::: "memory");
          else         asm volatile("s_waitcnt vmcnt(0)" ::: "memory");
          __builtin_amdgcn_sched_barrier(0);
          const int sl = it & 1;
          f32x4 f0 = sl ? *(f32x4*)&fB0 : *(f32x4*)&fA0;
          f32x4 f1 = sl ? *(f32x4*)&fB1 : *(f32x4*)&fA1;
          us8 h0;
#pragma unroll
          for (int i = 0; i < 4; ++i) {
            h0[i]     = bf(f0[i]);
            h0[4 + i] = bf(f1[i]);
          }
          *(us8*)&AH[sl][sr_ * 40 + sc_] = h0;
          asm volatile("s_waitcnt lgkmcnt(0)" ::: "memory");
          __builtin_amdgcn_s_barrier();
          __builtin_amdgcn_sched_barrier(0);
          short8 wh_ = sl ? *(short8*)&wB : *(short8*)&wA;
#pragma unroll
          for (int bt = 0; bt < 4; ++bt) {
            short8 ah = *(const short8*)&AH[sl][(bt * 16 + l15) * 40 + kg * 8];
            acc[bt] = __builtin_amdgcn_mfma_f32_16x16x32_bf16(ah, wh_, acc[bt], 0, 0, 0);
          }
          if (it < 14) {
            if (sl) { ISSUE_X(it + 2, fB0, fB1, wB); }
            else    { ISSUE_X(it + 2, fA0, fA1, wA); }
          }
          __builtin_amdgcn_s_barrier();   // stage(it+1) must not race MFMA readers
        }
      } else {
        // ---- bf16 acts path (r or h), depth-2 pipeline, 2 loads/iter ----
        const unsigned short* actbase =
            (ks == 1) ? (Rbh + (size_t)(b0g + sr_) * DM + (kc0 - 512) + sc_)
                      : (Hbh + (size_t)(b0g + sr_) * HID + (kc0 - 1024) + sc_);
        u32x4 aA, wA, aB, wB;
        ISSUE_B(0, aA, wA);
        ISSUE_B(1, aB, wB);
#pragma unroll
        for (int it = 0; it < 16; ++it) {
          if (it < 15) asm volatile("s_waitcnt vmcnt(2)" ::: "memory");
          else         asm volatile("s_waitcnt vmcnt(0)" ::: "memory");
          __builtin_amdgcn_sched_barrier(0);
          const int sl = it & 1;
          u32x4 av = sl ? aB : aA;
          *(u32x4*)&AH[sl][sr_ * 40 + sc_] = av;
          asm volatile("s_waitcnt lgkmcnt(0)" ::: "memory");
          __builtin_amdgcn_s_barrier();
          __builtin_amdgcn_sched_barrier(0);
          short8 wh_ = sl ? *(short8*)&wB : *(short8*)&wA;
#pragma unroll
          for (int bt = 0; bt < 4; ++bt) {
            short8 ah = *(const short8*)&AH[sl][(bt * 16 + l15) * 40 + kg * 8];
            acc[bt] = __builtin_amdgcn_mfma_f32_16x16x32_bf16(ah, wh_, acc[bt], 0, 0, 0);
          }
          if (it < 14) {
            if (sl) { ISSUE_B(it + 2, aB, wB); }
            else    { ISSUE_B(it + 2, aA, wA); }
          }
          __builtin_amdgcn_s_barrier();   // stage(it+1) must not race MFMA readers
        }
      }

      // P partials: write THROUGH to LLC (cross-XCD consumers)
#pragma unroll
      for (int bt = 0; bt < 4; ++bt)
#pragma unroll
        for (int i = 0; i < 4; ++i)
          stf_llc(&P[((size_t)ks * BSZ + b0g + bt * 16 + kg * 4 + i) * VC + colb + jh + l15],
                  acc[bt][i]);
    }
    gsync(bar);

    // ================= pair phase (blocks 0..511, waves 0..1, 1 pair each) ==========
    if (blk < 512 && wave < 2) {
      const int pair = blk * 2 + wave;
      const int b = pair >> 3, n = pair & 7;
      const int l = lane;
      const float* Pb = P + (size_t)b * VC;
      float hv[3];
#pragma unroll
      for (int s = 0; s < 3; ++s) {
        int c = s * 512 + n * 64 + l;
        float sr2 = 0.f, sz = 0.f;
#pragma unroll
        for (int ksi = 0; ksi < 5; ++ksi) {
          const float* q = Pb + (size_t)ksi * BSZ * VC;
          sr2 += ldf_llc(q + c);
          sz  += ldf_llc(q + 1536 + c);
        }
        float gin = ldf_llc(Pb + 3072 + c) + ldf_llc(Pb + (size_t)BSZ * VC + 3072 + c);
        float ghn = 0.f;
#pragma unroll
        for (int ksi = 2; ksi < 5; ++ksi)
          ghn += ldf_llc(Pb + (size_t)ksi * BSZ * VC + 4608 + c);
        float rg = 1.f / (1.f + __expf(-(sr2 + bih[c] + bhh[c])));
        float zg = 1.f / (1.f + __expf(-(sz + bih[1536 + c] + bhh[1536 + c])));
        float nn = tanhf(gin + bih[3072 + c] + rg * (ghn + bhh[3072 + c]));
        float hnew = (1.f - zg) * nn + zg * hprev[s];
        hprev[s] = hnew;
        size_t hix = (size_t)b * HID + c;
        st16_llc(&Hbh[hix], bf(hnew));
        hv[s] = hnew;
      }
      float ssq = hv[0] * hv[0], ssk = hv[1] * hv[1];
#pragma unroll
      for (int off = 32; off > 0; off >>= 1) {
        ssq += __shfl_xor(ssq, off);
        ssk += __shfl_xor(ssk, off);
      }
      float qn = hv[0] * rsqrtf(ssq);
      float kn = hv[1] * rsqrtf(ssk);
      float ke = kn > 0.f ? kn : expm1f(kn);   // elu(unitnorm)
      kS[wave][l] = ke;
      qS[wave][l] = qn;                        // wave-local LDS: lockstep, no block sync

      float vvl = hv[2];
      float* Arow = &Alds[wave][l * 65];       // stride 65: 2 lanes/bank = conflict-free
      float racc = 0.f;
#pragma unroll
      for (int q4 = 0; q4 < 16; ++q4) {
        float a0 = Arow[q4 * 4 + 0], a1 = Arow[q4 * 4 + 1];
        float a2 = Arow[q4 * 4 + 2], a3 = Arow[q4 * 4 + 3];
        float k0 = kS[wave][q4 * 4 + 0], k1 = kS[wave][q4 * 4 + 1];
        float k2 = kS[wave][q4 * 4 + 2], k3 = kS[wave][q4 * 4 + 3];
        float q0 = qS[wave][q4 * 4 + 0], q1 = qS[wave][q4 * 4 + 1];
        float q2 = qS[wave][q4 * 4 + 2], q3 = qS[wave][q4 * 4 + 3];
        a0 += k0 * vvl; a1 += k1 * vvl; a2 += k2 * vvl; a3 += k3 * vvl;
        racc += q0 * a0 + q1 * a1 + q2 * a2 + q3 * a3;
        Arow[q4 * 4 + 0] = a0; Arow[q4 * 4 + 1] = a1;
        Arow[q4 * 4 + 2] = a2; Arow[q4 * 4 + 3] = a3;
      }
      size_t ri = (size_t)b * DM + n * 64 + l;
      st16_llc(&Rbh[ri], bf(racc));

      if (t == SEQ - 1) {
        r32[ri] = racc;                        // final r (plain; kernel-end flush)
        dout[65536  + pair * 64 + l] = ke;     // k output (f32)
        dout[131072 + pair * 64 + l] = qn;     // q output (f32)
      }
    }
    gsync(bar);
  }
}

// ---------------- final: out = r @ Wo.T + bo (f32) ----------------
__global__ __launch_bounds__(512) void out_gemm(const float* __restrict__ r32,
                                                const float* __restrict__ Wo,
                                                const float* __restrict__ bo,
                                                float* __restrict__ dout) {
  int b0 = blockIdx.x * 2;
  int o  = threadIdx.x;
  __shared__ float rL0[512];
  __shared__ float rL1[512];
  rL0[o] = r32[(size_t)b0 * DM + o];
  rL1[o] = r32[(size_t)(b0 + 1) * DM + o];
  __syncthreads();
  float a0 = bo[o], a1 = a0;
  const float* wrow = Wo + (size_t)o * DM;
  for (int c = 0; c < DM; ++c) {
    float w = wrow[c];
    a0 += rL0[c] * w;
    a1 += rL1[c] * w;
  }
  dout[(size_t)b0 * DM + o]       = a0;
  dout[(size_t)(b0 + 1) * DM + o] = a1;
}

extern "C" void kernel_launch(void* const* d_in, const int* in_sizes, int n_in,
                              void* d_out, int out_size, void* d_ws, size_t ws_size,
                              hipStream_t stream) {
  // Defensive input identification by element count (deterministic).
  int ix = 0, iwih = 1, iwhh = 2, ibih = 3, ibhh = 4, iwo = 5, ibo = 6;
  {
    int b1 = -1, b2 = -1;
    for (int i = 0; i < n_in; ++i) {
      int s = in_sizes[i];
      if      (s == SEQ * BSZ * DM) ix = i;
      else if (s == 4608 * 1024)    iwih = i;
      else if (s == 4608 * 1536)    iwhh = i;
      else if (s == DM * DM)        iwo = i;
      else if (s == DM)             ibo = i;
      else if (s == 4608)           { if (b1 < 0) b1 = i; else b2 = i; }
    }
    if (b1 >= 0) ibih = b1;
    if (b2 >= 0) ibhh = b2;
  }
  const float* x   = (const float*)d_in[ix];
  const float* Wih = (const float*)d_in[iwih];
  const float* Whh = (const float*)d_in[iwhh];
  const float* bih = (const float*)d_in[ibih];
  const float* bhh = (const float*)d_in[ibhh];
  const float* Wo  = (const float*)d_in[iwo];
  const float* bo  = (const float*)d_in[ibo];

  char* ws = (char*)d_ws;
  unsigned short* Wh  = (unsigned short*)(ws + OFF_WBH);
  float*          r32 = (float*)(ws + OFF_R32);
  unsigned*       bar = (unsigned*)(ws + OFF_BAR);
  float* dout = (float*)d_out;

  pk_wb  <<<11520, 256, 0, stream>>>(Wih, Whh, Wh, bar);
  pk_zero<<<256,   256, 0, stream>>>((f32x4*)(ws + OFF_RBH));
  fused  <<<NBLK,  256, 0, stream>>>(x, bih, bhh, ws, dout);
  out_gemm<<<64, 512, 0, stream>>>(r32, Wo, bo, dout);
}